// Round 1
// 211.477 us; speedup vs baseline: 1.0192x; 1.0192x over previous
//
#include <hip/hip_runtime.h>
#include <math.h>

// CRF negative log-likelihood. Round 6: persistent-wave software pipeline.
// B=16384, M=16, D=128, L=26. 2 batches per wave, 4 pairs per wave over
// 512 resident blocks (2/CU). Per iteration: issue next pair's X loads ->
// recurrence of current pair (loads in flight under ~1.2us of DS/VALU work)
// -> MFMA next pair. Breaks the load-phase / recurrence-phase serialization
// that made crf ~= sum of phases instead of max.
//
// v_s[j] = 2^{alpha_s[j] + e2[s][j] - s*delta};  v_0 = E_0;
// v_s = (v_{s-1} . P') * E_s,  P'[k][j] = 2^{T2[k][j] - delta} (constant),
// E_s[j] = 2^{e2[s][j]} (MFMA emissions, exponentiated once).

#define B_TOT 16384
#define M_LEN 16
#define D_DIM 128
#define L_LAB 26
#define WPB 4
#define NBLK 512                          // 2 blocks per CU, all resident
#define NWAVES (NBLK * WPB)               // 2048 waves
#define ITERS (B_TOT / (2 * NWAVES))      // 4 pairs per wave
#define LOG2E 1.4426950408889634f
#define LN2   0.6931471805599453f
#define DELTA 5.7f
#define ESTR 36                           // Ee row stride in floats (144 B)

typedef short v8s __attribute__((ext_vector_type(8)));   // 8 bf16
typedef float v4f __attribute__((ext_vector_type(4)));   // 4 fp32 acc

static __device__ __forceinline__ unsigned bf16u(float f) {
    unsigned u = __float_as_uint(f);
    u += 0x7fff + ((u >> 16) & 1);     // RNE
    return u >> 16;
}
static __device__ __forceinline__ unsigned pkbf(float lo, float hi) {
    return bf16u(lo) | (bf16u(hi) << 16);
}
// single-instruction RNE pack (same bits as pkbf for finite inputs)
static __device__ __forceinline__ unsigned cvtpk(float lo, float hi) {
    unsigned r;
    asm("v_cvt_pk_bf16_f32 %0, %1, %2" : "=v"(r) : "v"(lo), "v"(hi));
    return r;
}
static __device__ __forceinline__ float fexp2(float x) {
#if __has_builtin(__builtin_amdgcn_exp2f)
    return __builtin_amdgcn_exp2f(x);
#else
    return exp2f(x);
#endif
}
static __device__ __forceinline__ float flog2(float x) {
#if __has_builtin(__builtin_amdgcn_logf)
    return __builtin_amdgcn_logf(x);
#else
    return log2f(x);
#endif
}

// Precompute (a) W MFMA B-fragments, bf16, scaled by log2e, labels zero-padded
// to 32; (b) P' transposed: wsP[j*32+k] = 2^{T[k][j]*log2e - delta}, zero pad.
__global__ void prep_kernel(const float* __restrict__ W, const float* __restrict__ T,
                            uint4* __restrict__ wsW, float* __restrict__ wsP) {
    const int l = threadIdx.x;       // 64 threads
    const int c16 = l & 15, quad = l >> 4;
    #pragma unroll
    for (int f = 0; f < 8; ++f) {
        const int tile = f >> 2, kk = f & 3;
        const int label = tile * 16 + c16;
        const int base = kk * 32 + quad * 8;
        unsigned d[4];
        #pragma unroll
        for (int p = 0; p < 4; ++p) {
            float a = 0.f, bb = 0.f;
            if (label < L_LAB) {
                a  = W[label * D_DIM + base + 2 * p]     * LOG2E;
                bb = W[label * D_DIM + base + 2 * p + 1] * LOG2E;
            }
            d[p] = pkbf(a, bb);
        }
        wsW[l * 8 + f] = make_uint4(d[0], d[1], d[2], d[3]);
    }
    for (int i = l; i < 1024; i += 64) {
        const int j = i >> 5, k = i & 31;
        wsP[i] = (j < L_LAB && k < L_LAB)
               ? exp2f(T[k * L_LAB + j] * LOG2E - DELTA) : 0.f;
    }
}

__global__ __launch_bounds__(256, 2) void crf_kernel(
    const float* __restrict__ X, const int* __restrict__ Y,
    const float* __restrict__ T, const uint4* __restrict__ wsW,
    const float* __restrict__ wsP, float* __restrict__ out)
{
    const int lane = threadIdx.x & 63;
    const int wave = threadIdx.x >> 6;
    const int g = lane >> 5;             // batch half
    const int j = lane & 31;             // label (valid < 26; 26..31 = zero pad)
    const int c16 = lane & 15;           // MFMA col / row-group
    const int quad = lane >> 4;

    __shared__ float Ts[L_LAB * L_LAB];                // natural units (edge)
    __shared__ float Ee[WPB][2][2][M_LEN * ESTR];      // [wave][buf][g]: E = 2^{e2}
    __shared__ float vrow[WPB][2][32];                 // 32 floats: 16B-aligned rows
    __shared__ float red[WPB];

    for (int i = threadIdx.x; i < L_LAB * L_LAB; i += 256) Ts[i] = T[i];

    // W fragments (bf16, pre-scaled) + P' columns — resident for whole kernel
    uint4 wf[8];
    #pragma unroll
    for (int f = 0; f < 8; ++f) wf[f] = wsW[lane * 8 + f];
    float4 Pc4[7];
    {
        const float4* pp = (const float4*)(wsP + j * 32);
        #pragma unroll
        for (int t = 0; t < 7; ++t) Pc4[t] = pp[t];
    }

    __syncthreads();   // Ts ready

    const int wid = blockIdx.x * WPB + wave;

    float4 px[16];           // prefetched X for one pair (statically indexed)
    int ysr = 0, ynr = 0;    // prefetched Y for that pair
    float ne_c = 0.f;        // node+edge carried for current pair
    float wsum = 0.f;

    // issue one pair's X + Y loads into registers
    auto LOADP = [&](int p) {
        const float* xr = X + (size_t)p * (2 * M_LEN * D_DIM) + c16 * D_DIM + quad * 8;
        #pragma unroll
        for (int g2 = 0; g2 < 2; ++g2) {
            #pragma unroll
            for (int kk = 0; kk < 4; ++kk) {
                const float4* xp = (const float4*)(xr + g2 * (M_LEN * D_DIM) + kk * 32);
                px[g2 * 8 + kk * 2]     = xp[0];
                px[g2 * 8 + kk * 2 + 1] = xp[1];
            }
        }
        if (j < M_LEN) {
            const int bb = p * 2 + g;
            ysr = Y[bb * M_LEN + j];
            ynr = (j < M_LEN - 1) ? Y[bb * M_LEN + j + 1] : 0;
        }
    };

    // emissions via MFMA from px, epilogue applies exp2 into Ee[wave][buf]
    auto MFMAP = [&](int buf) {
        #pragma unroll
        for (int g2 = 0; g2 < 2; ++g2) {
            v4f acc0 = {0.f, 0.f, 0.f, 0.f};
            v4f acc1 = {0.f, 0.f, 0.f, 0.f};
            #pragma unroll
            for (int kk = 0; kk < 4; ++kk) {
                const float4 xa = px[g2 * 8 + kk * 2];
                const float4 xc = px[g2 * 8 + kk * 2 + 1];
                uint4 au = make_uint4(cvtpk(xa.x, xa.y), cvtpk(xa.z, xa.w),
                                      cvtpk(xc.x, xc.y), cvtpk(xc.z, xc.w));
                v8s af = *(v8s*)&au;
                v8s b0 = *(v8s*)&wf[kk];
                v8s b1 = *(v8s*)&wf[4 + kk];
                acc0 = __builtin_amdgcn_mfma_f32_16x16x32_bf16(af, b0, acc0, 0, 0, 0);
                acc1 = __builtin_amdgcn_mfma_f32_16x16x32_bf16(af, b1, acc1, 0, 0, 0);
            }
            // C layout: col = lane&15 (label), row s = quad*4 + r (position)
            #pragma unroll
            for (int r = 0; r < 4; ++r) {
                const int s = quad * 4 + r;
                Ee[wave][buf][g2][s * ESTR + c16]      = fexp2(acc0[r]);
                Ee[wave][buf][g2][s * ESTR + 16 + c16] = fexp2(acc1[r]);  // labels>=26: e2=0 -> E=1
            }
        }
    };

    // node + edge potentials (e2 recovered via log2(E)); uses ysr/ynr + Ee[buf]
    auto NODE = [&](int buf) -> float {
        float ne = 0.f;
        if (j < M_LEN) {                   // lanes 0-15 (g=0) and 32-47 (g=1)
            ne = flog2(Ee[wave][buf][g][j * ESTR + ysr]) * LN2;
            if (j < M_LEN - 1) ne += Ts[ysr * L_LAB + ynr];
        }
        ne += __shfl_xor(ne, 8);
        ne += __shfl_xor(ne, 4);
        ne += __shfl_xor(ne, 2);
        ne += __shfl_xor(ne, 1);           // valid where (lane&31)==0
        return ne;
    };

    // ---- prologue: pair 0 ----
    LOADP(wid);
    MFMAP(0);
    ne_c = NODE(0);

    for (int it = 0; it < ITERS; ++it) {
        const int buf = it & 1;

        // issue next pair's global loads FIRST; they fly under the recurrence
        if (it < ITERS - 1) LOADP((it + 1) * NWAVES + wid);
        __builtin_amdgcn_sched_barrier(0);   // don't let LLVM sink the loads

        // per-step E_s[j] preload (out of the serial RAW chain)
        float Ejs[M_LEN - 1];
        #pragma unroll
        for (int s = 1; s < M_LEN; ++s) Ejs[s - 1] = Ee[wave][buf][g][s * ESTR + j];

        // v_0 = E_0 (28 floats, replicated per lane)
        float4 v4[7];
        {
            const float4* e0 = (const float4*)&Ee[wave][buf][g][0];
            #pragma unroll
            for (int t = 0; t < 7; ++t) v4[t] = e0[t];
        }
        const float ne = ne_c;

        // ---- recurrence: 15 x (fp32 matvec + elementwise E) ----
        #pragma unroll
        for (int s = 1; s < M_LEN; ++s) {
            float4 u4 = make_float4(0.f, 0.f, 0.f, 0.f);
            #pragma unroll
            for (int t = 0; t < 7; ++t) {
                u4.x = fmaf(v4[t].x, Pc4[t].x, u4.x);
                u4.y = fmaf(v4[t].y, Pc4[t].y, u4.y);
                u4.z = fmaf(v4[t].z, Pc4[t].z, u4.z);
                u4.w = fmaf(v4[t].w, Pc4[t].w, u4.w);
            }
            const float u = (u4.x + u4.z) + (u4.y + u4.w);
            vrow[wave][g][j] = u * Ejs[s - 1];     // j>=26: Pc cols zero -> writes 0
            const float4* vr = (const float4*)&vrow[wave][g][0];
            #pragma unroll
            for (int t = 0; t < 7; ++t) v4[t] = vr[t];   // 7x ds_read_b128 (broadcast)
        }

        // ---- log partition (pad entries are 0 after step 15) ----
        float4 sv = make_float4(0.f, 0.f, 0.f, 0.f);
        #pragma unroll
        for (int t = 0; t < 7; ++t) {
            sv.x += v4[t].x; sv.y += v4[t].y; sv.z += v4[t].z; sv.w += v4[t].w;
        }
        const float logz = (flog2((sv.x + sv.z) + (sv.y + sv.w))
                            + (float)(M_LEN - 1) * DELTA) * LN2;

        float local = logz - ne;               // valid at lane 0 (g=0), lane 32 (g=1)
        const float other = __shfl(local, 32);
        if (lane == 0) wsum += local + other;

        // ---- drain prefetched pair: MFMA + node/edge for next iteration ----
        if (it < ITERS - 1) {
            MFMAP(buf ^ 1);
            ne_c = NODE(buf ^ 1);
        }
    }

    if (lane == 0) red[wave] = wsum;
    __syncthreads();
    if (threadIdx.x == 0) atomicAdd(out, (red[0] + red[1]) + (red[2] + red[3]));
}

extern "C" void kernel_launch(void* const* d_in, const int* in_sizes, int n_in,
                              void* d_out, int out_size, void* d_ws, size_t ws_size,
                              hipStream_t stream) {
    const float* X = (const float*)d_in[0];
    const int*   Y = (const int*)d_in[1];
    const float* W = (const float*)d_in[2];
    const float* T = (const float*)d_in[3];
    float* out = (float*)d_out;
    uint4* wsW = (uint4*)d_ws;                         // 8 KB
    float* wsP = (float*)((char*)d_ws + 8192);         // 4 KB

    hipMemsetAsync(out, 0, sizeof(float), stream);
    prep_kernel<<<1, 64, 0, stream>>>(W, T, wsW, wsP);
    crf_kernel<<<NBLK, 256, 0, stream>>>(X, Y, T, wsW, wsP, out);
}

// Round 2
// 207.802 us; speedup vs baseline: 1.0373x; 1.0177x over previous
//
#include <hip/hip_runtime.h>
#include <math.h>

// CRF negative log-likelihood. Round 7: fold prep into crf (single dispatch).
// B=16384, M=16, D=128, L=26. 2 batches per wave, 4 pairs per wave over
// 512 resident blocks (2/CU). Persistent software pipeline: issue next pair's
// X loads -> recurrence of current pair -> MFMA next pair. crf is HBM-bound
// (134 MB X read = 21.3 us floor); prologue prep (W fragments + P' columns)
// now rides under the pair-0 X load latency instead of a separate kernel.
//
// v_s[j] = 2^{alpha_s[j] + e2[s][j] - s*delta};  v_0 = E_0;
// v_s = (v_{s-1} . P') * E_s,  P'[k][j] = 2^{T2[k][j] - delta} (constant),
// E_s[j] = 2^{e2[s][j]} (MFMA emissions, exponentiated once).

#define B_TOT 16384
#define M_LEN 16
#define D_DIM 128
#define L_LAB 26
#define WPB 4
#define NBLK 512                          // 2 blocks per CU, all resident
#define NWAVES (NBLK * WPB)               // 2048 waves
#define ITERS (B_TOT / (2 * NWAVES))      // 4 pairs per wave
#define LOG2E 1.4426950408889634f
#define LN2   0.6931471805599453f
#define DELTA 5.7f
#define ESTR 36                           // Ee row stride in floats (144 B)

typedef short v8s __attribute__((ext_vector_type(8)));   // 8 bf16
typedef float v4f __attribute__((ext_vector_type(4)));   // 4 fp32 acc

// single-instruction RNE pack (verified bit-identical to manual RNE: absmax 0.0)
static __device__ __forceinline__ unsigned cvtpk(float lo, float hi) {
    unsigned r;
    asm("v_cvt_pk_bf16_f32 %0, %1, %2" : "=v"(r) : "v"(lo), "v"(hi));
    return r;
}
static __device__ __forceinline__ float fexp2(float x) {
#if __has_builtin(__builtin_amdgcn_exp2f)
    return __builtin_amdgcn_exp2f(x);
#else
    return exp2f(x);
#endif
}
static __device__ __forceinline__ float flog2(float x) {
#if __has_builtin(__builtin_amdgcn_logf)
    return __builtin_amdgcn_logf(x);
#else
    return log2f(x);
#endif
}

__global__ __launch_bounds__(256, 2) void crf_kernel(
    const float* __restrict__ X, const int* __restrict__ Y,
    const float* __restrict__ W, const float* __restrict__ T,
    float* __restrict__ out)
{
    const int lane = threadIdx.x & 63;
    const int wave = threadIdx.x >> 6;
    const int g = lane >> 5;             // batch half
    const int j = lane & 31;             // label (valid < 26; 26..31 = zero pad)
    const int c16 = lane & 15;           // MFMA col / row-group
    const int quad = lane >> 4;

    __shared__ float Ts[L_LAB * L_LAB];                // natural units (edge)
    __shared__ float Ee[WPB][2][2][M_LEN * ESTR];      // [wave][buf][g]: E = 2^{e2}
    __shared__ float vrow[WPB][2][32];                 // 32 floats: 16B-aligned rows
    __shared__ float red[WPB];

    const int wid = blockIdx.x * WPB + wave;

    float4 px[16];           // prefetched X for one pair (statically indexed)
    int ysr = 0, ynr = 0;    // prefetched Y for that pair
    float ne_c = 0.f;        // node+edge carried for current pair
    float wsum = 0.f;

    // issue one pair's X + Y loads into registers
    auto LOADP = [&](int p) {
        const float* xr = X + (size_t)p * (2 * M_LEN * D_DIM) + c16 * D_DIM + quad * 8;
        #pragma unroll
        for (int g2 = 0; g2 < 2; ++g2) {
            #pragma unroll
            for (int kk = 0; kk < 4; ++kk) {
                const float4* xp = (const float4*)(xr + g2 * (M_LEN * D_DIM) + kk * 32);
                px[g2 * 8 + kk * 2]     = xp[0];
                px[g2 * 8 + kk * 2 + 1] = xp[1];
            }
        }
        if (j < M_LEN) {
            const int bb = p * 2 + g;
            ysr = Y[bb * M_LEN + j];
            ynr = (j < M_LEN - 1) ? Y[bb * M_LEN + j + 1] : 0;
        }
    };

    // ---- issue pair-0 loads FIRST; prep work below hides under their latency
    LOADP(wid);
    __builtin_amdgcn_sched_barrier(0);

    // ---- in-block prep: W MFMA B-fragments (bf16, pre-scaled by log2e) ----
    uint4 wf[8];
    #pragma unroll
    for (int f = 0; f < 8; ++f) {
        const int tile = f >> 2, kk = f & 3;
        const int label = tile * 16 + c16;
        const int base = kk * 32 + quad * 8;
        unsigned d0 = 0, d1 = 0, d2 = 0, d3 = 0;
        if (label < L_LAB) {
            const float4* wp = (const float4*)(W + label * D_DIM + base);
            const float4 wa = wp[0], wb = wp[1];
            d0 = cvtpk(wa.x * LOG2E, wa.y * LOG2E);
            d1 = cvtpk(wa.z * LOG2E, wa.w * LOG2E);
            d2 = cvtpk(wb.x * LOG2E, wb.y * LOG2E);
            d3 = cvtpk(wb.z * LOG2E, wb.w * LOG2E);
        }
        wf[f] = make_uint4(d0, d1, d2, d3);
    }

    // ---- in-block prep: P' columns, Pc[k] = 2^{T[k][j]*log2e - delta} ----
    float4 Pc4[7];
    #pragma unroll
    for (int t = 0; t < 7; ++t) {
        float c[4];
        #pragma unroll
        for (int cc = 0; cc < 4; ++cc) {
            const int k = t * 4 + cc;
            c[cc] = (j < L_LAB && k < L_LAB)
                  ? fexp2(T[k * L_LAB + j] * LOG2E - DELTA) : 0.f;
        }
        Pc4[t] = make_float4(c[0], c[1], c[2], c[3]);
    }

    // ---- stage T to LDS for edge potentials ----
    for (int i = threadIdx.x; i < L_LAB * L_LAB; i += 256) Ts[i] = T[i];

    // emissions via MFMA from px, epilogue applies exp2 into Ee[wave][buf]
    auto MFMAP = [&](int buf) {
        #pragma unroll
        for (int g2 = 0; g2 < 2; ++g2) {
            v4f acc0 = {0.f, 0.f, 0.f, 0.f};
            v4f acc1 = {0.f, 0.f, 0.f, 0.f};
            #pragma unroll
            for (int kk = 0; kk < 4; ++kk) {
                const float4 xa = px[g2 * 8 + kk * 2];
                const float4 xc = px[g2 * 8 + kk * 2 + 1];
                uint4 au = make_uint4(cvtpk(xa.x, xa.y), cvtpk(xa.z, xa.w),
                                      cvtpk(xc.x, xc.y), cvtpk(xc.z, xc.w));
                v8s af = *(v8s*)&au;
                v8s b0 = *(v8s*)&wf[kk];
                v8s b1 = *(v8s*)&wf[4 + kk];
                acc0 = __builtin_amdgcn_mfma_f32_16x16x32_bf16(af, b0, acc0, 0, 0, 0);
                acc1 = __builtin_amdgcn_mfma_f32_16x16x32_bf16(af, b1, acc1, 0, 0, 0);
            }
            // C layout: col = lane&15 (label), row s = quad*4 + r (position)
            #pragma unroll
            for (int r = 0; r < 4; ++r) {
                const int s = quad * 4 + r;
                Ee[wave][buf][g2][s * ESTR + c16]      = fexp2(acc0[r]);
                Ee[wave][buf][g2][s * ESTR + 16 + c16] = fexp2(acc1[r]);  // labels>=26: e2=0 -> E=1
            }
        }
    };

    // node + edge potentials (e2 recovered via log2(E)); uses ysr/ynr + Ee[buf]
    auto NODE = [&](int buf) -> float {
        float ne = 0.f;
        if (j < M_LEN) {                   // lanes 0-15 (g=0) and 32-47 (g=1)
            ne = flog2(Ee[wave][buf][g][j * ESTR + ysr]) * LN2;
            if (j < M_LEN - 1) ne += Ts[ysr * L_LAB + ynr];
        }
        ne += __shfl_xor(ne, 8);
        ne += __shfl_xor(ne, 4);
        ne += __shfl_xor(ne, 2);
        ne += __shfl_xor(ne, 1);           // valid where (lane&31)==0
        return ne;
    };

    __syncthreads();   // Ts ready (also drains pair-0 px loads, needed by MFMAP)

    // ---- prologue: pair 0 ----
    MFMAP(0);
    ne_c = NODE(0);

    for (int it = 0; it < ITERS; ++it) {
        const int buf = it & 1;

        // issue next pair's global loads FIRST; they fly under the recurrence
        if (it < ITERS - 1) LOADP((it + 1) * NWAVES + wid);
        __builtin_amdgcn_sched_barrier(0);   // don't let LLVM sink the loads

        // per-step E_s[j] preload (out of the serial RAW chain)
        float Ejs[M_LEN - 1];
        #pragma unroll
        for (int s = 1; s < M_LEN; ++s) Ejs[s - 1] = Ee[wave][buf][g][s * ESTR + j];

        // v_0 = E_0 (28 floats, replicated per lane)
        float4 v4[7];
        {
            const float4* e0 = (const float4*)&Ee[wave][buf][g][0];
            #pragma unroll
            for (int t = 0; t < 7; ++t) v4[t] = e0[t];
        }
        const float ne = ne_c;

        // ---- recurrence: 15 x (fp32 matvec + elementwise E) ----
        #pragma unroll
        for (int s = 1; s < M_LEN; ++s) {
            float4 u4 = make_float4(0.f, 0.f, 0.f, 0.f);
            #pragma unroll
            for (int t = 0; t < 7; ++t) {
                u4.x = fmaf(v4[t].x, Pc4[t].x, u4.x);
                u4.y = fmaf(v4[t].y, Pc4[t].y, u4.y);
                u4.z = fmaf(v4[t].z, Pc4[t].z, u4.z);
                u4.w = fmaf(v4[t].w, Pc4[t].w, u4.w);
            }
            const float u = (u4.x + u4.z) + (u4.y + u4.w);
            vrow[wave][g][j] = u * Ejs[s - 1];     // j>=26: Pc cols zero -> writes 0
            const float4* vr = (const float4*)&vrow[wave][g][0];
            #pragma unroll
            for (int t = 0; t < 7; ++t) v4[t] = vr[t];   // 7x ds_read_b128 (broadcast)
        }

        // ---- log partition (pad entries are 0 after step 15) ----
        float4 sv = make_float4(0.f, 0.f, 0.f, 0.f);
        #pragma unroll
        for (int t = 0; t < 7; ++t) {
            sv.x += v4[t].x; sv.y += v4[t].y; sv.z += v4[t].z; sv.w += v4[t].w;
        }
        const float logz = (flog2((sv.x + sv.z) + (sv.y + sv.w))
                            + (float)(M_LEN - 1) * DELTA) * LN2;

        float local = logz - ne;               // valid at lane 0 (g=0), lane 32 (g=1)
        const float other = __shfl(local, 32);
        if (lane == 0) wsum += local + other;

        // ---- drain prefetched pair: MFMA + node/edge for next iteration ----
        if (it < ITERS - 1) {
            MFMAP(buf ^ 1);
            ne_c = NODE(buf ^ 1);
        }
    }

    if (lane == 0) red[wave] = wsum;
    __syncthreads();
    if (threadIdx.x == 0) atomicAdd(out, (red[0] + red[1]) + (red[2] + red[3]));
}

extern "C" void kernel_launch(void* const* d_in, const int* in_sizes, int n_in,
                              void* d_out, int out_size, void* d_ws, size_t ws_size,
                              hipStream_t stream) {
    const float* X = (const float*)d_in[0];
    const int*   Y = (const int*)d_in[1];
    const float* W = (const float*)d_in[2];
    const float* T = (const float*)d_in[3];
    float* out = (float*)d_out;

    hipMemsetAsync(out, 0, sizeof(float), stream);
    crf_kernel<<<NBLK, 256, 0, stream>>>(X, Y, W, T, out);
}